// Round 17
// baseline (1702.972 us; speedup 1.0000x reference)
//
#include <hip/hip_runtime.h>
#include <math.h>

// 3-layer LSTM (H=64, T=512, B=2048, Din=16), R17: two-group ping-pong.
// R16 post-mortem: deferred store neutral -> residual stall is the serial
// MFMA-phase/cell-phase chain shared by all waves. R17 splits the block's 8
// batch rows into P (rows 0-3, waves 0-7) and Q (rows 4-7, waves 8-15) in
// anti-phase: interval1 = {P: h-MFMA(t); Q: cell(t-1)}, interval2 = {P:
// cell(t); Q: h-MFMA(t)}. Each barrier interval overlaps one group's MFMA
// latency chain with the other's transcendental chain on disjoint waves.
// Per group: 8 waves x 2 tiles (R14 pattern), 4-row h plane, x planes pack
// 4 steps (x-pass once/4 iters). Epilogue: Q-cell(T-1). Arithmetic identical
// to R15/R16 -> absmax must reproduce exactly 9.765625e-4.

#define T_STEPS 512
#define BATCH   2048
#define HID     64
#define CB      8
#define NTHR    1024
#define SEQS    (BATCH * HID)     // hseq u32 elements per timestep
#define PL      1024              // fp16 elems per x buffer (16 rows x 64)

typedef __attribute__((ext_vector_type(8))) _Float16 f16x8;
typedef __attribute__((ext_vector_type(4))) float f32x4;

__device__ __forceinline__ float sigm(float z) { return 1.0f / (1.0f + __expf(-z)); }
__device__ __forceinline__ float tanh_f(float z) {
    z = fminf(15.0f, fmaxf(-15.0f, z));
    const float e = __expf(2.0f * z);
    return (e - 1.0f) / (e + 1.0f);
}
__device__ __forceinline__ short tb(float v) { return (short)(__float_as_uint(v) >> 16); }
__device__ __forceinline__ float fb(unsigned h) {
    return __uint_as_float((h & 0xffffu) << 16);
}
// 4-row fp16 h plane (rows alias &3), XOR-swizzled 16B units
__device__ __forceinline__ int ha4(int row, int u8) {
    row &= 3;
    return row * 128 + ((u8 ^ row) << 4);
}
__device__ __forceinline__ void hwr4(_Float16* p, int row, int u, _Float16 v) {
    *(_Float16*)((char*)p + ha4(row, u >> 3) + (u & 7) * 2) = v;
}
__device__ __forceinline__ f16x8 hrd4(const _Float16* p, int row, int u8) {
    return *(const f16x8*)((const char*)p + ha4(row, u8));
}
// 16-row fp16 x plane (row = 4*slot + batch), XOR on row&7
__device__ __forceinline__ int xaddr(int row, int u8) {
    return row * 128 + ((u8 ^ (row & 7)) << 4);
}
__device__ __forceinline__ void xwr16(_Float16* p, int row, int k, _Float16 v) {
    *(_Float16*)((char*)p + xaddr(row, k >> 3) + (k & 7) * 2) = v;
}
__device__ __forceinline__ f16x8 xrd16(const _Float16* p, int row, int u8) {
    return *(const f16x8*)((const char*)p + xaddr(row, u8));
}

#define MFMA16(A, B, C)  __builtin_amdgcn_mfma_f32_16x16x32_f16((A), (B), (C), 0, 0, 0)

// x-side pass over plane BASE -> both tiles (covers 4 timesteps; bias init)
#define X_PASS(DA, DB, BASE) do {                                             \
    DA[0] = biasA; DA[1] = biasA; DA[2] = biasA; DA[3] = biasA;               \
    DB[0] = biasB; DB[1] = biasB; DB[2] = biasB; DB[3] = biasB;               \
    {                                                                         \
        const f16x8 ax0 = xrd16((BASE), arow, 0 + ksub);                      \
        DA = MFMA16(ax0, WIA0, DA);                                           \
        DB = MFMA16(ax0, WIB0, DB);                                           \
    }                                                                         \
    if (Din > 32) {                                                           \
        const f16x8 ax1 = xrd16((BASE), arow, 4 + ksub);                      \
        DA = MFMA16(ax1, WIA1, DA);                                           \
        DB = MFMA16(ax1, WIB1, DB);                                           \
    }                                                                         \
} while (0)

// one LSTM cell update for this thread's (cb,cu); uses gts/hp/hout/cst
#define CELL_BODY() do {                                                      \
    const float gi = gts[cb * 256 + cu];                                      \
    const float gf = gts[cb * 256 + 64 + cu];                                 \
    const float gg = gts[cb * 256 + 128 + cu];                                \
    const float go = gts[cb * 256 + 192 + cu];                                \
    cst = sigm(gf) * cst + sigm(gi) * tanh_f(gg);                             \
    hcell = sigm(go) * tanh_f(cst);                                           \
    hwr4(hp, cb, cu, (_Float16)hcell);                                        \
    if (store_h) {                                                            \
        const short hh_ = tb(hcell);                                          \
        const short hl_ = tb(hcell - fb((unsigned)(unsigned short)hh_));      \
        *hout = (unsigned)(unsigned short)hh_ |                               \
                ((unsigned)(unsigned short)hl_ << 16);                        \
    }                                                                         \
} while (0)

__device__ __forceinline__ f16x8 ldw16(const float* p) {
    const float4 a = *(const float4*)p;
    const float4 b = *(const float4*)(p + 4);
    f16x8 w;
    w[0]=(_Float16)a.x; w[1]=(_Float16)a.y; w[2]=(_Float16)a.z; w[3]=(_Float16)a.w;
    w[4]=(_Float16)b.x; w[5]=(_Float16)b.y; w[6]=(_Float16)b.z; w[7]=(_Float16)b.w;
    return w;
}

__global__
__attribute__((amdgpu_flat_work_group_size(NTHR, NTHR),
               amdgpu_waves_per_eu(4, 4)))
void lstm_layer(
    const float* __restrict__ x0,    // layer0 input [B][T][16] fp32, or null
    unsigned*    __restrict__ hseq,  // [T][B][64] packed bf16 hi|lo<<16
    const float* __restrict__ Wih,   // [256][Din]
    const float* __restrict__ Whh,   // [256][64]
    const float* __restrict__ bih,   // [256]
    const float* __restrict__ bhh,   // [256]
    const float* __restrict__ Wout,  // [7][64] (head only)
    const float* __restrict__ bout,  // [7]
    float* __restrict__ out,         // [B][7]
    int Din, int store_h, int do_head)
{
    __shared__ __attribute__((aligned(16))) _Float16 xpP[2 * PL], xpQ[2 * PL];
    __shared__ __attribute__((aligned(16))) _Float16 hpP[4 * 64], hpQ[4 * 64];
    __shared__ __attribute__((aligned(16))) float gtsP[4 * 256], gtsQ[4 * 256];
    __shared__ __attribute__((aligned(16))) float hf[8 * HID];

    const int tid  = threadIdx.x;
    const int lane = tid & 63;
    const int wid  = tid >> 6;           // 0..15
    const bool isP = (wid < 8);
    const int gwid = wid & 7;            // wave within group
    const int ncolA = gwid * 32 + (lane & 15);
    const int ncolB = ncolA + 16;
    const int ksub = (lane >> 4) & 3;
    const int arow = lane & 15;
    const int b0   = blockIdx.x * CB;
    const int gb0  = b0 + (isP ? 0 : 4); // group's first global batch row

    _Float16* const xp0 = isP ? xpP : xpQ;
    _Float16* const hp  = isP ? hpP : hpQ;
    float*    const gts = isP ? gtsP : gtsQ;

    // roles within the group
    const bool isCell = isP ? (tid < 256) : (tid >= 512 && tid < 768);
    const bool isStg  = isP ? (tid >= 256 && tid < 512) : (tid >= 768);
    const int ci = (isP ? tid : tid - 512) & 255;     // cell-local index
    const int cb = ci >> 6, cu = ci & 63;
    const int si = (isP ? tid - 256 : tid - 768) & 255; // staging-local index
    const int sbh = (si >> 6) & 3, su = si & 63;        // hseq staging coords
    const int sbx = (si >> 4) & 15, sk = si & 15;       // x0 staging coords

    // ---- weight fragments: 1-term fp16, two tiles per wave ----
    f16x8 WIA0 = {0,0,0,0,0,0,0,0}, WIA1 = {0,0,0,0,0,0,0,0};
    f16x8 WIB0 = {0,0,0,0,0,0,0,0}, WIB1 = {0,0,0,0,0,0,0,0};
    f16x8 WHA0, WHA1, WHB0, WHB1;
    {
        const int k0 = ksub * 8;
        if (k0 < Din) {
            WIA0 = ldw16(Wih + ncolA * Din + k0);
            WIB0 = ldw16(Wih + ncolB * Din + k0);
        }
        if (Din > 32) {
            WIA1 = ldw16(Wih + ncolA * Din + 32 + k0);
            WIB1 = ldw16(Wih + ncolB * Din + 32 + k0);
        }
        WHA0 = ldw16(Whh + ncolA * HID + k0);
        WHA1 = ldw16(Whh + ncolA * HID + 32 + k0);
        WHB0 = ldw16(Whh + ncolB * HID + k0);
        WHB1 = ldw16(Whh + ncolB * HID + 32 + k0);
    }
    const float biasA = bih[ncolA] + bhh[ncolA];
    const float biasB = bih[ncolB] + bhh[ncolB];

    // ---- zero planes ----
    ((unsigned*)xpP)[tid] = 0;                  // 2*PL fp16 = 1024 u32
    ((unsigned*)xpQ)[tid] = 0;
    if (tid < 128) ((unsigned*)hpP)[tid] = 0;
    else if (tid < 256) ((unsigned*)hpQ)[tid - 128] = 0;
    __syncthreads();

    // ---- prologue: stage steps 0..7 into this group's two x buffers ----
    if (isStg) {
        if (x0) {
            if (si < 64) {
                #pragma unroll
                for (int s8 = 0; s8 < 8; ++s8) {
                    const float v = x0[(size_t)(gb0 + sbx) * (T_STEPS * 16) + s8 * 16 + sk];
                    xwr16(xp0 + (s8 >> 2) * PL, (s8 & 3) * 4 + sbx, sk, (_Float16)v);
                }
            }
        } else {
            #pragma unroll
            for (int s8 = 0; s8 < 8; ++s8) {
                const unsigned p = hseq[(size_t)s8 * SEQS + (gb0 + sbh) * HID + su];
                xwr16(xp0 + (s8 >> 2) * PL, (s8 & 3) * 4 + sbh, su,
                      (_Float16)(fb(p) + fb(p >> 16)));
            }
        }
    }
    __syncthreads();

    // ---- prologue: x contribution (+bias) for group of steps 0..3 ----
    f32x4 CxA, CxB;
    f32x4 CxnA = {0.f,0.f,0.f,0.f}, CxnB = {0.f,0.f,0.f,0.f};
    X_PASS(CxA, CxB, xp0);

    float cst = 0.0f, hcell = 0.0f;
    float pxn = 0.0f; unsigned phn = 0;   // staging value (Q: crosses iters)

    // running pointers
    const unsigned* hin = hseq + (size_t)8 * SEQS + (size_t)(gb0 + sbh) * HID + su;
    const float* xin = x0 ? x0 + (size_t)(gb0 + sbx) * (T_STEPS * 16) + 8 * 16 + sk
                          : nullptr;
    unsigned* hout = hseq + (size_t)(gb0 + cb) * HID + cu;
    if (!isP) hout -= SEQS;   // Q's cell at iter t handles step t-1

    for (int t = 0; t < T_STEPS; ++t) {
        const int s = t & 3, g = t >> 2;

        // ================= interval 1: P-MFMA(t) | Q-cell(t-1) ============
        if (isP) {
            if (isStg && t + 8 < T_STEPS) {           // issue load, step t+8
                if (x0) { if (si < 64) pxn = *xin; }
                else phn = *hin;
            }
            const f16x8 ah0 = hrd4(hp, arow, ksub);
            const f16x8 ah1 = hrd4(hp, arow, 4 + ksub);
            f32x4 GA = MFMA16(ah0, WHA0, CxA); GA = MFMA16(ah1, WHA1, GA);
            f32x4 GB = MFMA16(ah0, WHB0, CxB); GB = MFMA16(ah1, WHB1, GB);
            if ((lane >> 4) == s) {
                #pragma unroll
                for (int j = 0; j < 4; ++j) {
                    gts[j * 256 + ncolA] = GA[j];
                    gts[j * 256 + ncolB] = GB[j];
                }
            }
        } else {
            if (isCell && t > 0) {
                CELL_BODY();                           // step t-1
            } else if (isStg && t > 0 && t + 7 < T_STEPS) {
                // plane write of value loaded last iter (step t+7)
                const int row4 = 4 * ((t + 7) & 3);
                _Float16* dst = xp0 + (((t + 7) >> 2) & 1) * PL;
                if (x0) {
                    if (si < 64) xwr16(dst, row4 + sbx, sk, (_Float16)pxn);
                } else {
                    xwr16(dst, row4 + sbh, su, (_Float16)(fb(phn) + fb(phn >> 16)));
                }
            }
        }
        __syncthreads();

        // ================= interval 2: P-cell(t) | Q-MFMA(t) ==============
        if (isP) {
            if (s == 0 && t + 4 < T_STEPS) X_PASS(CxnA, CxnB, xp0 + ((g + 1) & 1) * PL);
            if (isCell) {
                CELL_BODY();                           // step t
                if (do_head && t == T_STEPS - 1) hf[cb * HID + cu] = hcell;
            } else if (isStg && t + 8 < T_STEPS) {
                // plane write of value loaded this iter (step t+8)
                _Float16* dst = xp0 + (g & 1) * PL;
                if (x0) {
                    if (si < 64) xwr16(dst, 4 * s + sbx, sk, (_Float16)pxn);
                } else {
                    xwr16(dst, 4 * s + sbh, su, (_Float16)(fb(phn) + fb(phn >> 16)));
                }
            }
        } else {
            if (isStg && t + 8 < T_STEPS) {           // issue load, step t+8
                if (x0) { if (si < 64) pxn = *xin; }
                else phn = *hin;
            }
            if (s == 0 && t + 4 < T_STEPS) X_PASS(CxnA, CxnB, xp0 + ((g + 1) & 1) * PL);
            const f16x8 ah0 = hrd4(hp, arow, ksub);
            const f16x8 ah1 = hrd4(hp, arow, 4 + ksub);
            f32x4 GA = MFMA16(ah0, WHA0, CxA); GA = MFMA16(ah1, WHA1, GA);
            f32x4 GB = MFMA16(ah0, WHB0, CxB); GB = MFMA16(ah1, WHB1, GB);
            if ((lane >> 4) == s) {
                #pragma unroll
                for (int j = 0; j < 4; ++j) {
                    gts[j * 256 + ncolA] = GA[j];
                    gts[j * 256 + ncolB] = GB[j];
                }
            }
        }
        __syncthreads();

        if (s == 3) { CxA = CxnA; CxB = CxnB; }       // group hand-off
        hin += SEQS;
        hout += SEQS;
        if (x0) xin += 16;
    }

    // ---- epilogue: Q-cell(T-1) (gtsQ written in last interval 2) ----
    if (!isP && isCell) {
        CELL_BODY();                                   // step T-1
        if (do_head) hf[(4 + cb) * HID + cu] = hcell;
    }
    __syncthreads();

    // ---- head: out = h2[T-1] @ Wout^T + bout ----
    if (do_head && tid < 7 * CB) {
        const int b = tid / 7, o = tid % 7;
        float a = bout[o];
        #pragma unroll
        for (int k = 0; k < HID; ++k)
            a = fmaf(hf[b * HID + k], Wout[o * HID + k], a);
        out[(b0 + b) * 7 + o] = a;
    }
}

extern "C" void kernel_launch(void* const* d_in, const int* in_sizes, int n_in,
                              void* d_out, int out_size, void* d_ws, size_t ws_size,
                              hipStream_t stream) {
    const float* x    = (const float*)d_in[0];
    const float* Wih0 = (const float*)d_in[1];
    const float* Whh0 = (const float*)d_in[2];
    const float* bih0 = (const float*)d_in[3];
    const float* bhh0 = (const float*)d_in[4];
    const float* Wih1 = (const float*)d_in[5];
    const float* Whh1 = (const float*)d_in[6];
    const float* bih1 = (const float*)d_in[7];
    const float* bhh1 = (const float*)d_in[8];
    const float* Wih2 = (const float*)d_in[9];
    const float* Whh2 = (const float*)d_in[10];
    const float* bih2 = (const float*)d_in[11];
    const float* bhh2 = (const float*)d_in[12];
    const float* Wout = (const float*)d_in[13];
    const float* bout = (const float*)d_in[14];
    float* out = (float*)d_out;
    unsigned* hseq = (unsigned*)d_ws;   // needs T*B*64*4 = 268,435,456 B

    const dim3 grid(BATCH / CB), blk(NTHR);
    lstm_layer<<<grid, blk, 0, stream>>>(x, hseq, Wih0, Whh0, bih0, bhh0,
                                         nullptr, nullptr, nullptr, 16, 1, 0);
    lstm_layer<<<grid, blk, 0, stream>>>(nullptr, hseq, Wih1, Whh1, bih1, bhh1,
                                         nullptr, nullptr, nullptr, HID, 1, 0);
    lstm_layer<<<grid, blk, 0, stream>>>(nullptr, hseq, Wih2, Whh2, bih2, bhh2,
                                         Wout, bout, out, HID, 0, 1);
}

// Round 18
// 1676.312 us; speedup vs baseline: 1.0159x; 1.0159x over previous
//
#include <hip/hip_runtime.h>
#include <math.h>

// 3-layer LSTM (H=64, T=512, B=2048, Din=16), R18: in-register cell, fixed.
// R13 retried with its failure mode removed. R13's quad-transpose cell was
// bit-correct (absmax matched) but slow because cell/staging split by
// HALF-WAVE (big divergent bodies serialize through exec mask). R18:
//  - no 2-step x pairing: A rows 8-15 are pure dups (h AND x planes read
//    with row&7 alias) -> ALL 16 C rows valid -> every lane computes a cell
//    every iter (lanes 32-63 compute redundant dups; removes the parity
//    guard, the shfl_xor cst migration, and divergence).
//  - tiny predicated tails only: hseq store lanes<32 (unique writer),
//    staging lanes>=32 (load hseq(t+3), write x-plane(t+2), ~4 instrs).
//  - x planes x4, mod-4 schedule: write step t+2 at iter t; read at t+1
//    (CxNext precompute) and consumed as CxCur at t+... 1 barrier per iter.
//  - gts buffer + 2 LDS trips + 1 barrier deleted from the critical path.
// Arithmetic identical to R15/R16 -> absmax must be exactly 9.765625e-4.

#define T_STEPS 512
#define BATCH   2048
#define HID     64
#define CB      8
#define NTHR    1024
#define SEQS    (BATCH * HID)     // hseq u32 elements per timestep

typedef __attribute__((ext_vector_type(8))) _Float16 f16x8;
typedef __attribute__((ext_vector_type(4))) float f32x4;

__device__ __forceinline__ float sigm(float z) { return 1.0f / (1.0f + __expf(-z)); }
__device__ __forceinline__ float tanh_f(float z) {
    z = fminf(15.0f, fmaxf(-15.0f, z));
    const float e = __expf(2.0f * z);
    return (e - 1.0f) / (e + 1.0f);
}
__device__ __forceinline__ short tb(float v) { return (short)(__float_as_uint(v) >> 16); }
__device__ __forceinline__ float fb(unsigned h) {
    return __uint_as_float((h & 0xffffu) << 16);
}
// 8-row fp16 plane, rows alias &7 (A rows 8-15 broadcast), XOR-swizzled 16B
__device__ __forceinline__ int pa(int row, int u8) {
    row &= 7;
    return row * 128 + ((u8 ^ row) << 4);
}
__device__ __forceinline__ void pwr(_Float16* p, int row, int u, _Float16 v) {
    *(_Float16*)((char*)p + pa(row, u >> 3) + (u & 7) * 2) = v;
}
__device__ __forceinline__ f16x8 prd(const _Float16* p, int row, int u8) {
    return *(const f16x8*)((const char*)p + pa(row, u8));
}
// DPP quad_perm lane permute (VALU pipe, no LDS)
template<int CTRL>
__device__ __forceinline__ float qp(float v) {
    return __int_as_float(__builtin_amdgcn_mov_dpp(__float_as_int(v), CTRL, 0xf, 0xf, true));
}

#define MFMA16(A, B, C)  __builtin_amdgcn_mfma_f32_16x16x32_f16((A), (B), (C), 0, 0, 0)

// x-side pass over an 8-row plane BASE -> DST (bias folded in)
#define X_PASS(DST, BASE) do {                                                \
    DST[0] = biasr; DST[1] = biasr; DST[2] = biasr; DST[3] = biasr;           \
    {                                                                         \
        const f16x8 ax0 = prd((BASE), arow, 0 + ksub);                        \
        DST = MFMA16(ax0, WIh0, DST);                                         \
    }                                                                         \
    if (Din > 32) {                                                           \
        const f16x8 ax1 = prd((BASE), arow, 4 + ksub);                        \
        DST = MFMA16(ax1, WIh1, DST);                                         \
    }                                                                         \
} while (0)

__device__ __forceinline__ f16x8 ldw16(const float* p) {
    const float4 a = *(const float4*)p;
    const float4 b = *(const float4*)(p + 4);
    f16x8 w;
    w[0]=(_Float16)a.x; w[1]=(_Float16)a.y; w[2]=(_Float16)a.z; w[3]=(_Float16)a.w;
    w[4]=(_Float16)b.x; w[5]=(_Float16)b.y; w[6]=(_Float16)b.z; w[7]=(_Float16)b.w;
    return w;
}

__global__ __launch_bounds__(NTHR) void lstm_layer(
    const float* __restrict__ x0,    // layer0 input [B][T][16] fp32, or null
    unsigned*    __restrict__ hseq,  // [T][B][64] packed bf16 hi|lo<<16
    const float* __restrict__ Wih,   // [256][Din]
    const float* __restrict__ Whh,   // [256][64]
    const float* __restrict__ bih,   // [256]
    const float* __restrict__ bhh,   // [256]
    const float* __restrict__ Wout,  // [7][64] (head only)
    const float* __restrict__ bout,  // [7]
    float* __restrict__ out,         // [B][7]
    int Din, int store_h, int do_head)
{
    __shared__ __attribute__((aligned(16))) _Float16 xp[4][8 * 64];
    __shared__ __attribute__((aligned(16))) _Float16 hp[2][8 * 64];
    __shared__ __attribute__((aligned(16))) float hf[8 * HID];

    const int tid  = threadIdx.x;
    const int lane = tid & 63;
    const int wid  = tid >> 6;           // 0..15
    const int c    = lane & 15;
    // quad-gate B-col mapping: gate on lane bits 0-1 (validated in R13)
    const int ncol = (c & 3) * 64 + wid * 4 + (c >> 2);
    const int ksub = (lane >> 4) & 3;
    const int arow = lane & 15;
    const int bloc = ((lane >> 4) & 1) * 4 + (c & 3);   // this lane's batch
    const int uloc = wid * 4 + (c >> 2);                // this lane's unit
    const int b0   = blockIdx.x * CB;
    const bool real = (lane >> 4) < 2;   // rows 0-7 (non-dup) lanes
    const bool stg  = lane >= 32;        // staging lanes
    const int se  = wid * 32 + (lane & 31);   // staging element 0..511
    const int sb  = se >> 6, su = se & 63;    // hseq staging coords
    const int sbx = se >> 4, sk = se & 15;    // x0 staging coords (se<128)

    // ---- weight fragments: 1-term fp16, resident for the whole kernel ----
    f16x8 WIh0 = {0,0,0,0,0,0,0,0}, WIh1 = {0,0,0,0,0,0,0,0};
    f16x8 WHh0, WHh1;
    {
        const int k0 = ksub * 8;
        if (k0 < Din) WIh0 = ldw16(Wih + ncol * Din + k0);
        if (Din > 32) WIh1 = ldw16(Wih + ncol * Din + 32 + k0);
        WHh0 = ldw16(Whh + ncol * HID + k0);
        WHh1 = ldw16(Whh + ncol * HID + 32 + k0);
    }
    const float biasr = bih[ncol] + bhh[ncol];

    // ---- zero planes: xp = 2048 fp16 = 1024 u32; hp = 512 u32 ----
    ((unsigned*)xp)[tid] = 0;
    if (tid < 512) ((unsigned*)hp)[tid] = 0;
    __syncthreads();

    // ---- prologue: stage steps 0,1 into planes 0,1; preload step 2 ----
    float sx = 0.0f; unsigned sh = 0;
    if (stg) {
        if (x0) {
            if (se < 128) {
                #pragma unroll
                for (int s = 0; s < 2; ++s) {
                    const float v = x0[(size_t)(b0 + sbx) * (T_STEPS * 16) + s * 16 + sk];
                    pwr(xp[s], sbx, sk, (_Float16)v);
                }
                sx = x0[(size_t)(b0 + sbx) * (T_STEPS * 16) + 2 * 16 + sk];
            }
        } else {
            #pragma unroll
            for (int s = 0; s < 2; ++s) {
                const unsigned p = hseq[(size_t)s * SEQS + (b0 + sb) * HID + su];
                pwr(xp[s], sb, su, (_Float16)(fb(p) + fb(p >> 16)));
            }
            sh = hseq[(size_t)2 * SEQS + (b0 + sb) * HID + su];
        }
    }
    __syncthreads();

    // ---- prologue: x contribution (+bias) for step 0 ----
    f32x4 CxCur; X_PASS(CxCur, xp[0]);
    f32x4 CxNext = {0.f, 0.f, 0.f, 0.f};

    float cst = 0.0f;   // per-lane c-state (dup lanes mirror their real twin)

    // running pointers
    const unsigned* hinp = hseq + (size_t)3 * SEQS + (size_t)(b0 + sb) * HID + su;
    const float* xinp = x0 ? x0 + (size_t)(b0 + sbx) * (T_STEPS * 16) + 3 * 16 + sk
                           : nullptr;
    unsigned* houtp = hseq + (size_t)(b0 + bloc) * HID + uloc;

    for (int t = 0; t < T_STEPS; ++t) {
        // ---- staging load issue for step t+3 (latency hidden, 3 iters) ----
        float nx = 0.0f; unsigned nh = 0;
        if (stg && t + 3 < T_STEPS) {
            if (x0) { if (se < 128) nx = *xinp; }
            else nh = *hinp;
        }

        // ---- h-side MFMA folded onto precomputed Cx(t) ----
        const f16x8 ah0 = prd(hp[(t + 1) & 1], arow, ksub);
        const f16x8 ah1 = prd(hp[(t + 1) & 1], arow, 4 + ksub);
        f32x4 G = MFMA16(ah0, WHh0, CxCur);
        G = MFMA16(ah1, WHh1, G);

        // ---- precompute Cx(t+1) from plane (t+1)&3 (off critical path) ----
        if (t + 1 < T_STEPS) X_PASS(CxNext, xp[(t + 1) & 3]);

        // ---- 4x4 gate<->batch quad transpose (pure VALU; R13-validated) ----
        const int p0 = c & 1, p1 = (c >> 1) & 1;
        const float q0 = qp<0xB1>(G[0]), q1 = qp<0xB1>(G[1]);
        const float q2 = qp<0xB1>(G[2]), q3 = qp<0xB1>(G[3]);
        const float t0 = p0 ? q1 : G[0];
        const float t1 = p0 ? G[1] : q0;
        const float t2 = p0 ? q3 : G[2];
        const float t3 = p0 ? G[3] : q2;
        const float s0 = qp<0x4E>(t0), s1 = qp<0x4E>(t1);
        const float s2 = qp<0x4E>(t2), s3 = qp<0x4E>(t3);
        const float gi = p1 ? s2 : t0;
        const float gf = p1 ? s3 : t1;
        const float gg = p1 ? t2 : s0;
        const float go = p1 ? t3 : s1;

        // ---- cell, ALL lanes (lanes 32-63 = redundant dups) ----
        cst = sigm(gf) * cst + sigm(gi) * tanh_f(gg);
        const float h = sigm(go) * tanh_f(cst);
        pwr(hp[t & 1], bloc, uloc, (_Float16)h);   // dup writes: same value
        if (store_h && real) {
            const short hh_ = tb(h);
            const short hl_ = tb(h - fb((unsigned)(unsigned short)hh_));
            *houtp = (unsigned)(unsigned short)hh_ |
                     ((unsigned)(unsigned short)hl_ << 16);
        }
        if (do_head && t == T_STEPS - 1 && real) hf[bloc * HID + uloc] = h;

        // ---- staging plane write: step t+2 -> plane (t+2)&3 ----
        if (stg && t + 2 < T_STEPS) {
            if (x0) { if (se < 128) pwr(xp[(t + 2) & 3], sbx, sk, (_Float16)sx); }
            else pwr(xp[(t + 2) & 3], sb, su, (_Float16)(fb(sh) + fb(sh >> 16)));
        }
        __syncthreads();

        CxCur = CxNext;
        sx = nx; sh = nh;
        hinp += SEQS;
        houtp += SEQS;
        if (x0) xinp += 16;
    }

    // ---- head: out = h2[T-1] @ Wout^T + bout ----
    if (do_head && tid < 7 * CB) {
        const int b = tid / 7, o = tid % 7;
        float a = bout[o];
        #pragma unroll
        for (int k = 0; k < HID; ++k)
            a = fmaf(hf[b * HID + k], Wout[o * HID + k], a);
        out[(b0 + b) * 7 + o] = a;
    }
}

extern "C" void kernel_launch(void* const* d_in, const int* in_sizes, int n_in,
                              void* d_out, int out_size, void* d_ws, size_t ws_size,
                              hipStream_t stream) {
    const float* x    = (const float*)d_in[0];
    const float* Wih0 = (const float*)d_in[1];
    const float* Whh0 = (const float*)d_in[2];
    const float* bih0 = (const float*)d_in[3];
    const float* bhh0 = (const float*)d_in[4];
    const float* Wih1 = (const float*)d_in[5];
    const float* Whh1 = (const float*)d_in[6];
    const float* bih1 = (const float*)d_in[7];
    const float* bhh1 = (const float*)d_in[8];
    const float* Wih2 = (const float*)d_in[9];
    const float* Whh2 = (const float*)d_in[10];
    const float* bih2 = (const float*)d_in[11];
    const float* bhh2 = (const float*)d_in[12];
    const float* Wout = (const float*)d_in[13];
    const float* bout = (const float*)d_in[14];
    float* out = (float*)d_out;
    unsigned* hseq = (unsigned*)d_ws;   // needs T*B*64*4 = 268,435,456 B

    const dim3 grid(BATCH / CB), blk(NTHR);
    lstm_layer<<<grid, blk, 0, stream>>>(x, hseq, Wih0, Whh0, bih0, bhh0,
                                         nullptr, nullptr, nullptr, 16, 1, 0);
    lstm_layer<<<grid, blk, 0, stream>>>(nullptr, hseq, Wih1, Whh1, bih1, bhh1,
                                         nullptr, nullptr, nullptr, HID, 1, 0);
    lstm_layer<<<grid, blk, 0, stream>>>(nullptr, hseq, Wih2, Whh2, bih2, bhh2,
                                         Wout, bout, out, HID, 0, 1);
}

// Round 19
// 1676.177 us; speedup vs baseline: 1.0160x; 1.0001x over previous
//
#include <hip/hip_runtime.h>
#include <math.h>

// 3-layer LSTM (H=64, T=512, B=2048, Din=16), R18: in-register cell, fixed.
// R13 retried with its failure mode removed. R13's quad-transpose cell was
// bit-correct (absmax matched) but slow because cell/staging split by
// HALF-WAVE (big divergent bodies serialize through exec mask). R18:
//  - no 2-step x pairing: A rows 8-15 are pure dups (h AND x planes read
//    with row&7 alias) -> ALL 16 C rows valid -> every lane computes a cell
//    every iter (lanes 32-63 compute redundant dups; removes the parity
//    guard, the shfl_xor cst migration, and divergence).
//  - tiny predicated tails only: hseq store lanes<32 (unique writer),
//    staging lanes>=32 (load hseq(t+3), write x-plane(t+2), ~4 instrs).
//  - x planes x4, mod-4 schedule: write step t+2 at iter t; read at t+1
//    (CxNext precompute) and consumed as CxCur at t+... 1 barrier per iter.
//  - gts buffer + 2 LDS trips + 1 barrier deleted from the critical path.
// Arithmetic identical to R15/R16 -> absmax must be exactly 9.765625e-4.

#define T_STEPS 512
#define BATCH   2048
#define HID     64
#define CB      8
#define NTHR    1024
#define SEQS    (BATCH * HID)     // hseq u32 elements per timestep

typedef __attribute__((ext_vector_type(8))) _Float16 f16x8;
typedef __attribute__((ext_vector_type(4))) float f32x4;

__device__ __forceinline__ float sigm(float z) { return 1.0f / (1.0f + __expf(-z)); }
__device__ __forceinline__ float tanh_f(float z) {
    z = fminf(15.0f, fmaxf(-15.0f, z));
    const float e = __expf(2.0f * z);
    return (e - 1.0f) / (e + 1.0f);
}
__device__ __forceinline__ short tb(float v) { return (short)(__float_as_uint(v) >> 16); }
__device__ __forceinline__ float fb(unsigned h) {
    return __uint_as_float((h & 0xffffu) << 16);
}
// 8-row fp16 plane, rows alias &7 (A rows 8-15 broadcast), XOR-swizzled 16B
__device__ __forceinline__ int pa(int row, int u8) {
    row &= 7;
    return row * 128 + ((u8 ^ row) << 4);
}
__device__ __forceinline__ void pwr(_Float16* p, int row, int u, _Float16 v) {
    *(_Float16*)((char*)p + pa(row, u >> 3) + (u & 7) * 2) = v;
}
__device__ __forceinline__ f16x8 prd(const _Float16* p, int row, int u8) {
    return *(const f16x8*)((const char*)p + pa(row, u8));
}
// DPP quad_perm lane permute (VALU pipe, no LDS)
template<int CTRL>
__device__ __forceinline__ float qp(float v) {
    return __int_as_float(__builtin_amdgcn_mov_dpp(__float_as_int(v), CTRL, 0xf, 0xf, true));
}

#define MFMA16(A, B, C)  __builtin_amdgcn_mfma_f32_16x16x32_f16((A), (B), (C), 0, 0, 0)

// x-side pass over an 8-row plane BASE -> DST (bias folded in)
#define X_PASS(DST, BASE) do {                                                \
    DST[0] = biasr; DST[1] = biasr; DST[2] = biasr; DST[3] = biasr;           \
    {                                                                         \
        const f16x8 ax0 = prd((BASE), arow, 0 + ksub);                        \
        DST = MFMA16(ax0, WIh0, DST);                                         \
    }                                                                         \
    if (Din > 32) {                                                           \
        const f16x8 ax1 = prd((BASE), arow, 4 + ksub);                        \
        DST = MFMA16(ax1, WIh1, DST);                                         \
    }                                                                         \
} while (0)

__device__ __forceinline__ f16x8 ldw16(const float* p) {
    const float4 a = *(const float4*)p;
    const float4 b = *(const float4*)(p + 4);
    f16x8 w;
    w[0]=(_Float16)a.x; w[1]=(_Float16)a.y; w[2]=(_Float16)a.z; w[3]=(_Float16)a.w;
    w[4]=(_Float16)b.x; w[5]=(_Float16)b.y; w[6]=(_Float16)b.z; w[7]=(_Float16)b.w;
    return w;
}

__global__ __launch_bounds__(NTHR) void lstm_layer(
    const float* __restrict__ x0,    // layer0 input [B][T][16] fp32, or null
    unsigned*    __restrict__ hseq,  // [T][B][64] packed bf16 hi|lo<<16
    const float* __restrict__ Wih,   // [256][Din]
    const float* __restrict__ Whh,   // [256][64]
    const float* __restrict__ bih,   // [256]
    const float* __restrict__ bhh,   // [256]
    const float* __restrict__ Wout,  // [7][64] (head only)
    const float* __restrict__ bout,  // [7]
    float* __restrict__ out,         // [B][7]
    int Din, int store_h, int do_head)
{
    __shared__ __attribute__((aligned(16))) _Float16 xp[4][8 * 64];
    __shared__ __attribute__((aligned(16))) _Float16 hp[2][8 * 64];
    __shared__ __attribute__((aligned(16))) float hf[8 * HID];

    const int tid  = threadIdx.x;
    const int lane = tid & 63;
    const int wid  = tid >> 6;           // 0..15
    const int c    = lane & 15;
    // quad-gate B-col mapping: gate on lane bits 0-1 (validated in R13)
    const int ncol = (c & 3) * 64 + wid * 4 + (c >> 2);
    const int ksub = (lane >> 4) & 3;
    const int arow = lane & 15;
    const int bloc = ((lane >> 4) & 1) * 4 + (c & 3);   // this lane's batch
    const int uloc = wid * 4 + (c >> 2);                // this lane's unit
    const int b0   = blockIdx.x * CB;
    const bool real = (lane >> 4) < 2;   // rows 0-7 (non-dup) lanes
    const bool stg  = lane >= 32;        // staging lanes
    const int se  = wid * 32 + (lane & 31);   // staging element 0..511
    const int sb  = se >> 6, su = se & 63;    // hseq staging coords
    const int sbx = se >> 4, sk = se & 15;    // x0 staging coords (se<128)

    // ---- weight fragments: 1-term fp16, resident for the whole kernel ----
    f16x8 WIh0 = {0,0,0,0,0,0,0,0}, WIh1 = {0,0,0,0,0,0,0,0};
    f16x8 WHh0, WHh1;
    {
        const int k0 = ksub * 8;
        if (k0 < Din) WIh0 = ldw16(Wih + ncol * Din + k0);
        if (Din > 32) WIh1 = ldw16(Wih + ncol * Din + 32 + k0);
        WHh0 = ldw16(Whh + ncol * HID + k0);
        WHh1 = ldw16(Whh + ncol * HID + 32 + k0);
    }
    const float biasr = bih[ncol] + bhh[ncol];

    // ---- zero planes: xp = 2048 fp16 = 1024 u32; hp = 512 u32 ----
    ((unsigned*)xp)[tid] = 0;
    if (tid < 512) ((unsigned*)hp)[tid] = 0;
    __syncthreads();

    // ---- prologue: stage steps 0,1 into planes 0,1; preload step 2 ----
    float sx = 0.0f; unsigned sh = 0;
    if (stg) {
        if (x0) {
            if (se < 128) {
                #pragma unroll
                for (int s = 0; s < 2; ++s) {
                    const float v = x0[(size_t)(b0 + sbx) * (T_STEPS * 16) + s * 16 + sk];
                    pwr(xp[s], sbx, sk, (_Float16)v);
                }
                sx = x0[(size_t)(b0 + sbx) * (T_STEPS * 16) + 2 * 16 + sk];
            }
        } else {
            #pragma unroll
            for (int s = 0; s < 2; ++s) {
                const unsigned p = hseq[(size_t)s * SEQS + (b0 + sb) * HID + su];
                pwr(xp[s], sb, su, (_Float16)(fb(p) + fb(p >> 16)));
            }
            sh = hseq[(size_t)2 * SEQS + (b0 + sb) * HID + su];
        }
    }
    __syncthreads();

    // ---- prologue: x contribution (+bias) for step 0 ----
    f32x4 CxCur; X_PASS(CxCur, xp[0]);
    f32x4 CxNext = {0.f, 0.f, 0.f, 0.f};

    float cst = 0.0f;   // per-lane c-state (dup lanes mirror their real twin)

    // running pointers
    const unsigned* hinp = hseq + (size_t)3 * SEQS + (size_t)(b0 + sb) * HID + su;
    const float* xinp = x0 ? x0 + (size_t)(b0 + sbx) * (T_STEPS * 16) + 3 * 16 + sk
                           : nullptr;
    unsigned* houtp = hseq + (size_t)(b0 + bloc) * HID + uloc;

    for (int t = 0; t < T_STEPS; ++t) {
        // ---- staging load issue for step t+3 (latency hidden, 3 iters) ----
        float nx = 0.0f; unsigned nh = 0;
        if (stg && t + 3 < T_STEPS) {
            if (x0) { if (se < 128) nx = *xinp; }
            else nh = *hinp;
        }

        // ---- h-side MFMA folded onto precomputed Cx(t) ----
        const f16x8 ah0 = prd(hp[(t + 1) & 1], arow, ksub);
        const f16x8 ah1 = prd(hp[(t + 1) & 1], arow, 4 + ksub);
        f32x4 G = MFMA16(ah0, WHh0, CxCur);
        G = MFMA16(ah1, WHh1, G);

        // ---- precompute Cx(t+1) from plane (t+1)&3 (off critical path) ----
        if (t + 1 < T_STEPS) X_PASS(CxNext, xp[(t + 1) & 3]);

        // ---- 4x4 gate<->batch quad transpose (pure VALU; R13-validated) ----
        const int p0 = c & 1, p1 = (c >> 1) & 1;
        const float q0 = qp<0xB1>(G[0]), q1 = qp<0xB1>(G[1]);
        const float q2 = qp<0xB1>(G[2]), q3 = qp<0xB1>(G[3]);
        const float t0 = p0 ? q1 : G[0];
        const float t1 = p0 ? G[1] : q0;
        const float t2 = p0 ? q3 : G[2];
        const float t3 = p0 ? G[3] : q2;
        const float s0 = qp<0x4E>(t0), s1 = qp<0x4E>(t1);
        const float s2 = qp<0x4E>(t2), s3 = qp<0x4E>(t3);
        const float gi = p1 ? s2 : t0;
        const float gf = p1 ? s3 : t1;
        const float gg = p1 ? t2 : s0;
        const float go = p1 ? t3 : s1;

        // ---- cell, ALL lanes (lanes 32-63 = redundant dups) ----
        cst = sigm(gf) * cst + sigm(gi) * tanh_f(gg);
        const float h = sigm(go) * tanh_f(cst);
        pwr(hp[t & 1], bloc, uloc, (_Float16)h);   // dup writes: same value
        if (store_h && real) {
            const short hh_ = tb(h);
            const short hl_ = tb(h - fb((unsigned)(unsigned short)hh_));
            *houtp = (unsigned)(unsigned short)hh_ |
                     ((unsigned)(unsigned short)hl_ << 16);
        }
        if (do_head && t == T_STEPS - 1 && real) hf[bloc * HID + uloc] = h;

        // ---- staging plane write: step t+2 -> plane (t+2)&3 ----
        if (stg && t + 2 < T_STEPS) {
            if (x0) { if (se < 128) pwr(xp[(t + 2) & 3], sbx, sk, (_Float16)sx); }
            else pwr(xp[(t + 2) & 3], sb, su, (_Float16)(fb(sh) + fb(sh >> 16)));
        }
        __syncthreads();

        CxCur = CxNext;
        sx = nx; sh = nh;
        hinp += SEQS;
        houtp += SEQS;
        if (x0) xinp += 16;
    }

    // ---- head: out = h2[T-1] @ Wout^T + bout ----
    if (do_head && tid < 7 * CB) {
        const int b = tid / 7, o = tid % 7;
        float a = bout[o];
        #pragma unroll
        for (int k = 0; k < HID; ++k)
            a = fmaf(hf[b * HID + k], Wout[o * HID + k], a);
        out[(b0 + b) * 7 + o] = a;
    }
}

extern "C" void kernel_launch(void* const* d_in, const int* in_sizes, int n_in,
                              void* d_out, int out_size, void* d_ws, size_t ws_size,
                              hipStream_t stream) {
    const float* x    = (const float*)d_in[0];
    const float* Wih0 = (const float*)d_in[1];
    const float* Whh0 = (const float*)d_in[2];
    const float* bih0 = (const float*)d_in[3];
    const float* bhh0 = (const float*)d_in[4];
    const float* Wih1 = (const float*)d_in[5];
    const float* Whh1 = (const float*)d_in[6];
    const float* bih1 = (const float*)d_in[7];
    const float* bhh1 = (const float*)d_in[8];
    const float* Wih2 = (const float*)d_in[9];
    const float* Whh2 = (const float*)d_in[10];
    const float* bih2 = (const float*)d_in[11];
    const float* bhh2 = (const float*)d_in[12];
    const float* Wout = (const float*)d_in[13];
    const float* bout = (const float*)d_in[14];
    float* out = (float*)d_out;
    unsigned* hseq = (unsigned*)d_ws;   // needs T*B*64*4 = 268,435,456 B

    const dim3 grid(BATCH / CB), blk(NTHR);
    lstm_layer<<<grid, blk, 0, stream>>>(x, hseq, Wih0, Whh0, bih0, bhh0,
                                         nullptr, nullptr, nullptr, 16, 1, 0);
    lstm_layer<<<grid, blk, 0, stream>>>(nullptr, hseq, Wih1, Whh1, bih1, bhh1,
                                         nullptr, nullptr, nullptr, HID, 1, 0);
    lstm_layer<<<grid, blk, 0, stream>>>(nullptr, hseq, Wih2, Whh2, bih2, bhh2,
                                         Wout, bout, out, HID, 0, 1);
}

// Round 20
// 874.034 us; speedup vs baseline: 1.9484x; 1.9177x over previous
//
#include <hip/hip_runtime.h>
#include <math.h>

// 3-layer LSTM (H=64, T=512, B=2048, Din=16), R19: fused 3-layer pipeline.
// ONE persistent dispatch; layer l processes timestep it-l (514 iters).
// The 2-barrier/iter latency overhead (proven irreducible in R14/R16/R17/R18)
// is amortized over 3 layers, and the hseq HBM round-trip (~1 GB) is deleted:
// inter-layer h flows through LDS fp16 planes. d_ws unused.
// Per block: 1024 thr = 16 waves, CB=8 batch rows, grid 256 (1 block/CU).
// Each wave owns one 16-col gate tile for ALL 3 layers (weights in 44 VGPRs;
// amdgpu_waves_per_eu(4,4) pins the 128-VGPR budget -- R14 proved it binds).
// Phase A: 7 shared ds_read_b128 + 11 MFMA per wave -> 3 gts buffers.
// Phase B: thr 0-511 = L0+L2 cells; thr 512-1023 = L1 cells + x staging.
// Numerics identical to R15 (fp16 1-term W, fp16 planes, fp32 cell state)
// -> absmax ~9.77e-4.

#define T_STEPS 512
#define BATCH   2048
#define HID     64
#define NG      256
#define CB      8
#define NTHR    1024

typedef __attribute__((ext_vector_type(8))) _Float16 f16x8;
typedef __attribute__((ext_vector_type(4))) float f32x4;

__device__ __forceinline__ float sigm(float z) { return 1.0f / (1.0f + __expf(-z)); }
__device__ __forceinline__ float tanh_f(float z) {
    z = fminf(15.0f, fmaxf(-15.0f, z));
    const float e = __expf(2.0f * z);
    return (e - 1.0f) / (e + 1.0f);
}
// 8-row 128B/row fp16 plane, XOR-swizzled 16B units; rows alias &7
__device__ __forceinline__ int pa(int row, int u8) {
    row &= 7;
    return row * 128 + ((u8 ^ row) << 4);
}
__device__ __forceinline__ void pwr(_Float16* p, int row, int u, _Float16 v) {
    *(_Float16*)((char*)p + pa(row, u >> 3) + (u & 7) * 2) = v;
}
__device__ __forceinline__ f16x8 prd(const _Float16* p, int row, int u8) {
    return *(const f16x8*)((const char*)p + pa(row, u8));
}

#define MFMA16(A, B, C)  __builtin_amdgcn_mfma_f32_16x16x32_f16((A), (B), (C), 0, 0, 0)

__device__ __forceinline__ f16x8 ldw16(const float* p) {
    const float4 a = *(const float4*)p;
    const float4 b = *(const float4*)(p + 4);
    f16x8 w;
    w[0]=(_Float16)a.x; w[1]=(_Float16)a.y; w[2]=(_Float16)a.z; w[3]=(_Float16)a.w;
    w[4]=(_Float16)b.x; w[5]=(_Float16)b.y; w[6]=(_Float16)b.z; w[7]=(_Float16)b.w;
    return w;
}

// gts writeout: C rows 8-15 are dups (planes alias row&7) -> lanes 0-31 write
#define GTS_STORE(GT, G) do {                                                 \
    if ((lane >> 4) < 2) {                                                    \
        float* gd = &(GT)[(lane >> 4) * 4 * NG + ncol];                       \
        gd[0]      = (G)[0];                                                  \
        gd[NG]     = (G)[1];                                                  \
        gd[2 * NG] = (G)[2];                                                  \
        gd[3 * NG] = (G)[3];                                                  \
    }                                                                         \
} while (0)

// cell update: reads gts row, updates CST, writes h to PLANE as fp16
#define CELL(GT, CST, PLANE, B_, U_, HOUT_) do {                              \
    const float* gsrc = &(GT)[(B_) * NG + (U_)];                              \
    const float gi = gsrc[0];                                                 \
    const float gf = gsrc[64];                                                \
    const float gg = gsrc[128];                                               \
    const float go = gsrc[192];                                               \
    CST = sigm(gf) * CST + sigm(gi) * tanh_f(gg);                             \
    HOUT_ = sigm(go) * tanh_f(CST);                                           \
    pwr((PLANE), (B_), (U_), (_Float16)HOUT_);                                \
} while (0)

__global__
__attribute__((amdgpu_flat_work_group_size(NTHR, NTHR),
               amdgpu_waves_per_eu(4, 4)))
void lstm3_fused(
    const float* __restrict__ x0,    // [B][T][16] fp32
    const float* __restrict__ Wih0,  // [256][16]
    const float* __restrict__ Whh0,  // [256][64]
    const float* __restrict__ bih0, const float* __restrict__ bhh0,
    const float* __restrict__ Wih1,  // [256][64]
    const float* __restrict__ Whh1,
    const float* __restrict__ bih1, const float* __restrict__ bhh1,
    const float* __restrict__ Wih2,
    const float* __restrict__ Whh2,
    const float* __restrict__ bih2, const float* __restrict__ bhh2,
    const float* __restrict__ Wout,  // [7][64]
    const float* __restrict__ bout,  // [7]
    float* __restrict__ out)         // [B][7]
{
    __shared__ __attribute__((aligned(16))) _Float16 xp[2][8 * 64];
    __shared__ __attribute__((aligned(16))) _Float16 h0p[8 * 64];
    __shared__ __attribute__((aligned(16))) _Float16 h1p[8 * 64];
    __shared__ __attribute__((aligned(16))) _Float16 h2p[8 * 64];
    __shared__ __attribute__((aligned(16))) float gt0[8 * NG];
    __shared__ __attribute__((aligned(16))) float gt1[8 * NG];
    __shared__ __attribute__((aligned(16))) float gt2[8 * NG];
    __shared__ __attribute__((aligned(16))) float hf[8 * HID];

    const int tid  = threadIdx.x;
    const int lane = tid & 63;
    const int wid  = tid >> 6;          // 0..15: N-tile index
    const int ncol = wid * 16 + (lane & 15);
    const int ksub = (lane >> 4) & 3;   // k-subgroup of 8
    const int arow = lane & 15;
    const int b0   = blockIdx.x * CB;

    // ---- weight fragments: 1-term fp16, all 3 layers resident (44 VGPR) ----
    const int k0 = ksub * 8;
    f16x8 WI0 = {0,0,0,0,0,0,0,0};
    if (k0 < 16) WI0 = ldw16(Wih0 + ncol * 16 + k0);
    const f16x8 WH00 = ldw16(Whh0 + ncol * HID + k0);
    const f16x8 WH01 = ldw16(Whh0 + ncol * HID + 32 + k0);
    const f16x8 WI10 = ldw16(Wih1 + ncol * HID + k0);
    const f16x8 WI11 = ldw16(Wih1 + ncol * HID + 32 + k0);
    const f16x8 WH10 = ldw16(Whh1 + ncol * HID + k0);
    const f16x8 WH11 = ldw16(Whh1 + ncol * HID + 32 + k0);
    const f16x8 WI20 = ldw16(Wih2 + ncol * HID + k0);
    const f16x8 WI21 = ldw16(Wih2 + ncol * HID + 32 + k0);
    const f16x8 WH20 = ldw16(Whh2 + ncol * HID + k0);
    const f16x8 WH21 = ldw16(Whh2 + ncol * HID + 32 + k0);
    const float bias0 = bih0[ncol] + bhh0[ncol];
    const float bias1 = bih1[ncol] + bhh1[ncol];
    const float bias2 = bih2[ncol] + bhh2[ncol];

    // ---- zero planes (xp: 512 u32; h planes: 256 u32 each) ----
    if (tid < 512) ((unsigned*)xp)[tid] = 0;
    else if (tid < 768) ((unsigned*)h0p)[tid - 512] = 0;
    if (tid >= 768) ((unsigned*)h1p)[tid - 768] = 0;
    if (tid < 256) ((unsigned*)h2p)[tid] = 0;
    __syncthreads();

    // ---- prologue: stage x(0)->buf0, x(1)->buf1 (threads 512-639) ----
    const int sidx = tid - 512;                 // staging index
    const int sbx = (sidx >> 4) & 7, sk = sidx & 15;
    const bool isStg = (tid >= 512) && (tid < 640);
    if (isStg) {
        #pragma unroll
        for (int s = 0; s < 2; ++s) {
            const float v = x0[(size_t)(b0 + sbx) * (T_STEPS * 16) + s * 16 + sk];
            pwr(xp[s], sbx, sk, (_Float16)v);
        }
    }
    __syncthreads();

    float cstA = 0.0f, cstB = 0.0f;   // tid<512: L0,L2 ; tid>=512: L1 (cstA)
    const float* xin = x0 + (size_t)(b0 + sbx) * (T_STEPS * 16) + 2 * 16 + sk;

    for (int it = 0; it < T_STEPS + 2; ++it) {
        const bool a0 = it < T_STEPS;
        const bool a1 = (it >= 1) && (it < T_STEPS + 1);
        const bool a2 = it >= 2;

        // ---- staging load issue: x(it+2) ----
        float pxn = 0.0f;
        if (isStg && it + 2 < T_STEPS) pxn = *xin;

        // ================= Phase A: MFMA for 3 layers =================
        {
            const f16x8 a00 = prd(h0p, arow, ksub);
            const f16x8 a01 = prd(h0p, arow, 4 + ksub);
            if (a0) {
                const f16x8 ax = prd(xp[it & 1], arow, ksub);
                f32x4 G = {bias0, bias0, bias0, bias0};
                G = MFMA16(ax, WI0, G);
                G = MFMA16(a00, WH00, G);
                G = MFMA16(a01, WH01, G);
                GTS_STORE(gt0, G);
            }
            const f16x8 a10 = prd(h1p, arow, ksub);
            const f16x8 a11 = prd(h1p, arow, 4 + ksub);
            if (a1) {
                f32x4 G = {bias1, bias1, bias1, bias1};
                G = MFMA16(a00, WI10, G);
                G = MFMA16(a01, WI11, G);
                G = MFMA16(a10, WH10, G);
                G = MFMA16(a11, WH11, G);
                GTS_STORE(gt1, G);
            }
            if (a2) {
                const f16x8 a20 = prd(h2p, arow, ksub);
                const f16x8 a21 = prd(h2p, arow, 4 + ksub);
                f32x4 G = {bias2, bias2, bias2, bias2};
                G = MFMA16(a10, WI20, G);
                G = MFMA16(a11, WI21, G);
                G = MFMA16(a20, WH20, G);
                G = MFMA16(a21, WH21, G);
                GTS_STORE(gt2, G);
            }
        }
        __syncthreads();

        // ================= Phase B: cells + staging =================
        if (tid < 512) {
            const int b = tid >> 6, u = tid & 63;
            float h;
            if (a0) CELL(gt0, cstA, h0p, b, u, h);
            if (a2) {
                CELL(gt2, cstB, h2p, b, u, h);
                if (it == T_STEPS + 1) hf[b * HID + u] = h;
            }
        } else {
            const int b = (tid - 512) >> 6, u = tid & 63;
            float h;
            if (a1) CELL(gt1, cstA, h1p, b, u, h);
            if (isStg && it + 2 < T_STEPS) pwr(xp[it & 1], sbx, sk, (_Float16)pxn);
        }
        __syncthreads();

        xin += 16;
    }

    // ---- head: out = h2[T-1] @ Wout^T + bout ----
    if (tid < 7 * CB) {
        const int b = tid / 7, o = tid % 7;
        float a = bout[o];
        #pragma unroll
        for (int k = 0; k < HID; ++k)
            a = fmaf(hf[b * HID + k], Wout[o * HID + k], a);
        out[(b0 + b) * 7 + o] = a;
    }
}

extern "C" void kernel_launch(void* const* d_in, const int* in_sizes, int n_in,
                              void* d_out, int out_size, void* d_ws, size_t ws_size,
                              hipStream_t stream) {
    const float* x    = (const float*)d_in[0];
    const float* Wih0 = (const float*)d_in[1];
    const float* Whh0 = (const float*)d_in[2];
    const float* bih0 = (const float*)d_in[3];
    const float* bhh0 = (const float*)d_in[4];
    const float* Wih1 = (const float*)d_in[5];
    const float* Whh1 = (const float*)d_in[6];
    const float* bih1 = (const float*)d_in[7];
    const float* bhh1 = (const float*)d_in[8];
    const float* Wih2 = (const float*)d_in[9];
    const float* Whh2 = (const float*)d_in[10];
    const float* bih2 = (const float*)d_in[11];
    const float* bhh2 = (const float*)d_in[12];
    const float* Wout = (const float*)d_in[13];
    const float* bout = (const float*)d_in[14];
    float* out = (float*)d_out;

    lstm3_fused<<<dim3(BATCH / CB), dim3(NTHR), 0, stream>>>(
        x, Wih0, Whh0, bih0, bhh0,
        Wih1, Whh1, bih1, bhh1,
        Wih2, Whh2, bih2, bhh2,
        Wout, bout, out);
}